// Round 6
// baseline (665.946 us; speedup 1.0000x reference)
//
#include <hip/hip_runtime.h>
#include <hip/hip_bf16.h>

typedef __attribute__((ext_vector_type(8))) short bf16x8;
typedef __attribute__((ext_vector_type(4))) float f32x4;
typedef unsigned int u32;
typedef unsigned short u16;

// ---- workspace layout (f32 elements) ----
// G2 = v^T k : [0, 262144)
// colsum(k)  : [262144, 262656)
// loss sum   : [262656]
// G1 = k^T k : [262912, 525056)
#define WS_G2     0
#define WS_COLSUM 262144
#define WS_LOSS   262656
#define WS_G1     262912
#define WS_END    525056

// ---- output layout (f32 elements) ----
#define OUT_LOSS 33554432
#define OUT_W    33554433
#define OUT_S    33816577

#define PA 72    // LDS pitch (shorts): conflict-free b128 frag reads

__device__ inline u32 pkbf2(float a, float b) {
    __hip_bfloat162 h2 = __float22bfloat162_rn(make_float2(a, b));
    u32 r;
    __builtin_memcpy(&r, &h2, 4);
    return r;
}

// =====================================================================
// K12: fused. grad = diffT@k is rewritten as W*(k^T k) - v^T k, so the
// two GEMM families are independent and fuse into one launch:
//  role A (16/24 of blocks): retrieved = k @ W.T (128x128 tile, BK=64),
//    epilogue: out writes + loss partial.  NO diffT (epilogue LDS pass
//    and its 4.7M bank conflicts deleted).
//  role B (8/24 of blocks): G1 = k^T k and G2 = v^T k (128x128 output
//    tiles, split-K=32 chunks of 2048), both operands transpose-staged
//    from fp32 (the proven k2 B-path), atomically accumulated into ws.
//    j-tile-0 k-product blocks also accumulate colsum(k).
// Role interleave in 24-block groups keeps xcd = bx&7 for BOTH roles'
// XCD swizzles, and mixes heterogeneous waves per CU for latency hiding.
// Both roles: single LDS buffer (18432 u16) + register prefetch issued
// after b2 -> loads overlap the MFMA phase, drain at next iter's b1.
// =====================================================================
__global__ __launch_bounds__(256, 3)
void k12(const float* __restrict__ kmat, const float* __restrict__ vmat,
         const float* __restrict__ Wmat, float* __restrict__ out,
         float* __restrict__ ws) {
    __shared__ u16 sm[18432];      // role A: A/B tiles.  role B: As/Bs tiles.
    __shared__ float red[4];

    const int tid = threadIdx.x;
    const int bx = blockIdx.x;                  // 3072 blocks
    const int g24 = bx / 24;                    // 0..127
    const int u   = bx - g24 * 24;              // 0..23; 24%8==0 so bx&7 == u&7
    const int wv = tid >> 6, lane = tid & 63;
    const int wm = wv & 1, wn = wv >> 1;
    const int col = lane & 15, kg = lane >> 4;
    const int rg = lane >> 4;

    if (u < 16) {
        // ================= role A: retrieved = k @ W.T =================
        const int idx = g24 * 16 + u;           // bijective [0,2048)
        const int xcd = idx & 7, slot = idx >> 3;
        const int rowtile = xcd * 64 + (slot >> 2), ntile = slot & 3;
        const long b0 = (long)rowtile * 128;
        const int vd0 = ntile * 128;

        const int srow = tid >> 4;              // 0..15
        const int scol = (tid & 15) * 4;        // 0..60

        f32x4 acc[4][4] = {};

        const float* gA = kmat + (b0 + srow) * 512 + scol;
        const float* gB = Wmat + (long)(vd0 + srow) * 512 + scol;

        float4 ra[8], rb[8];
#pragma unroll
        for (int i = 0; i < 8; ++i) {
            ra[i] = *(const float4*)(gA + (long)i * 16 * 512);
            rb[i] = *(const float4*)(gB + (long)i * 16 * 512);
        }

        for (int it = 0; it < 8; ++it) {
            __syncthreads();   // b1: all waves done reading LDS for it-1
#pragma unroll
            for (int i = 0; i < 8; ++i) {
                int r = i * 16 + srow;
                *(uint2*)&sm[r * PA + scol] = make_uint2(pkbf2(ra[i].x, ra[i].y), pkbf2(ra[i].z, ra[i].w));
                *(uint2*)&sm[9216 + r * PA + scol] = make_uint2(pkbf2(rb[i].x, rb[i].y), pkbf2(rb[i].z, rb[i].w));
            }
            __syncthreads();   // b2: tile it visible
            if (it < 7) {
                gA += 64; gB += 64;
#pragma unroll
                for (int i = 0; i < 8; ++i) {
                    ra[i] = *(const float4*)(gA + (long)i * 16 * 512);
                    rb[i] = *(const float4*)(gB + (long)i * 16 * 512);
                }
            }
#pragma unroll
            for (int kk = 0; kk < 2; ++kk) {
                bf16x8 af[4], bfr[4];
#pragma unroll
                for (int i = 0; i < 4; ++i)
                    af[i] = *(const bf16x8*)&sm[(wm * 64 + i * 16 + col) * PA + kk * 32 + kg * 8];
#pragma unroll
                for (int j = 0; j < 4; ++j)
                    bfr[j] = *(const bf16x8*)&sm[9216 + (wn * 64 + j * 16 + col) * PA + kk * 32 + kg * 8];
#pragma unroll
                for (int i = 0; i < 4; ++i)
#pragma unroll
                    for (int j = 0; j < 4; ++j)
                        acc[i][j] = __builtin_amdgcn_mfma_f32_16x16x32_bf16(af[i], bfr[j], acc[i][j], 0, 0, 0);
            }
        }

        // epilogue: out writes + loss partial (no diffT)
        float lossp = 0.f;
#pragma unroll
        for (int i = 0; i < 4; ++i) {
#pragma unroll
            for (int j = 0; j < 4; ++j) {
                int r0 = wm * 64 + i * 16 + rg * 4;
                int c  = wn * 64 + j * 16 + col;
                long gb = b0 + r0;
#pragma unroll
                for (int r = 0; r < 4; ++r) {
                    float rv = acc[i][j][r];
                    long gidx = (gb + r) * 512 + vd0 + c;
                    out[gidx] = rv;
                    float dv = rv - vmat[gidx];
                    lossp += dv * dv;
                }
            }
        }
#pragma unroll
        for (int m = 32; m; m >>= 1) lossp += __shfl_xor(lossp, m);
        if (lane == 0) red[wv] = lossp;
        __syncthreads();
        if (tid == 0) atomicAdd(&ws[WS_LOSS], red[0] + red[1] + red[2] + red[3]);

    } else {
        // ============ role B: G1 = k^T k (pi=0), G2 = v^T k (pi=1) ============
        const int idx = g24 * 8 + (u - 16);     // bijective [0,1024)
        const int xcd = idx & 7, slot = idx >> 3;   // slot 0..127
        const int chunk = xcd * 4 + (slot >> 5);    // 4 chunks per XCD
        const int ot = slot & 31;                   // output tile id
        const int pi = ot >> 4;                     // 0: A=k -> G1, 1: A=v -> G2
        const int i0 = ((ot >> 2) & 3) * 128;       // output row tile (A cols)
        const int j0 = (ot & 3) * 128;              // output col tile (k cols)
        const long b0 = (long)chunk * 2048;

        const float* Asrc = pi ? vmat : kmat;
        const int bcol = (tid & 63) * 2;            // column pair 0..126
        const int bq = wv * 16;                     // row quarter base

        f32x4 acc[4][4] = {};
        float cs0 = 0.f, cs1 = 0.f;

        const float* gA0 = Asrc + (b0 + bq) * 512 + i0 + bcol;
        const float* gB0 = kmat + (b0 + bq) * 512 + j0 + bcol;

        float2 rA[16], rB[16];
#pragma unroll
        for (int i = 0; i < 16; ++i) {
            rA[i] = *(const float2*)(gA0 + (long)i * 512);
            rB[i] = *(const float2*)(gB0 + (long)i * 512);
        }

        for (int it = 0; it < 32; ++it) {
            __syncthreads();   // b1: prev MFMA reads done; rA/rB(it) drained
            {   // pack A(it) -> As, B(it) -> Bs; colsum from rB
                u32 a0[8], a1[8], p0[8], p1[8];
#pragma unroll
                for (int i = 0; i < 16; ++i) { cs0 += rB[i].x; cs1 += rB[i].y; }
#pragma unroll
                for (int i = 0; i < 8; ++i) {
                    a0[i] = pkbf2(rA[2 * i].x, rA[2 * i + 1].x);
                    a1[i] = pkbf2(rA[2 * i].y, rA[2 * i + 1].y);
                    p0[i] = pkbf2(rB[2 * i].x, rB[2 * i + 1].x);
                    p1[i] = pkbf2(rB[2 * i].y, rB[2 * i + 1].y);
                }
                *(uint4*)&sm[bcol * PA + bq]           = make_uint4(a0[0], a0[1], a0[2], a0[3]);
                *(uint4*)&sm[bcol * PA + bq + 8]       = make_uint4(a0[4], a0[5], a0[6], a0[7]);
                *(uint4*)&sm[(bcol + 1) * PA + bq]     = make_uint4(a1[0], a1[1], a1[2], a1[3]);
                *(uint4*)&sm[(bcol + 1) * PA + bq + 8] = make_uint4(a1[4], a1[5], a1[6], a1[7]);
                *(uint4*)&sm[9216 + bcol * PA + bq]           = make_uint4(p0[0], p0[1], p0[2], p0[3]);
                *(uint4*)&sm[9216 + bcol * PA + bq + 8]       = make_uint4(p0[4], p0[5], p0[6], p0[7]);
                *(uint4*)&sm[9216 + (bcol + 1) * PA + bq]     = make_uint4(p1[0], p1[1], p1[2], p1[3]);
                *(uint4*)&sm[9216 + (bcol + 1) * PA + bq + 8] = make_uint4(p1[4], p1[5], p1[6], p1[7]);
            }
            __syncthreads();   // b2: tile it visible
            if (it < 31) {     // prefetch it+1 AFTER b2 -> overlaps MFMAs
                const float* gan = gA0 + (long)(it + 1) * 64 * 512;
                const float* gbn = gB0 + (long)(it + 1) * 64 * 512;
#pragma unroll
                for (int i = 0; i < 16; ++i) {
                    rA[i] = *(const float2*)(gan + (long)i * 512);
                    rB[i] = *(const float2*)(gbn + (long)i * 512);
                }
            }
#pragma unroll
            for (int kk = 0; kk < 2; ++kk) {
                bf16x8 af[4], bfr[4];
#pragma unroll
                for (int i = 0; i < 4; ++i)
                    af[i] = *(const bf16x8*)&sm[(wm * 64 + i * 16 + col) * PA + kk * 32 + kg * 8];
#pragma unroll
                for (int j = 0; j < 4; ++j)
                    bfr[j] = *(const bf16x8*)&sm[9216 + (wn * 64 + j * 16 + col) * PA + kk * 32 + kg * 8];
#pragma unroll
                for (int i = 0; i < 4; ++i)
#pragma unroll
                    for (int j = 0; j < 4; ++j)
                        acc[i][j] = __builtin_amdgcn_mfma_f32_16x16x32_bf16(af[i], bfr[j], acc[i][j], 0, 0, 0);
            }
        }

        // accumulate into G1/G2
        float* G = ws + (pi ? WS_G2 : WS_G1);
#pragma unroll
        for (int i = 0; i < 4; ++i)
#pragma unroll
            for (int j = 0; j < 4; ++j)
#pragma unroll
                for (int r = 0; r < 4; ++r) {
                    int orow = i0 + wm * 64 + i * 16 + rg * 4 + r;
                    int ocol = j0 + wn * 64 + j * 16 + col;
                    atomicAdd(&G[orow * 512 + ocol], acc[i][j][r]);
                }

        // colsum(k): exactly the pi=0, i0=0 blocks (ot 0..3) cover all cols
        if (ot < 4) {
            __syncthreads();
            float* cred = (float*)sm;   // [128][4]
            cred[bcol * 4 + wv] = cs0;
            cred[(bcol + 1) * 4 + wv] = cs1;
            __syncthreads();
            if (tid < 128) {
                float s = cred[tid * 4] + cred[tid * 4 + 1] + cred[tid * 4 + 2] + cred[tid * 4 + 3];
                atomicAdd(&ws[WS_COLSUM + j0 + tid], s);
            }
        }
    }
}

// =====================================================================
// K3: gates + grad = 2/(B*VD)*(W@G1 - G2) + new_W/new_S + loss finalize
// grid 512: block = one vd row; W row staged in LDS; G1 cols read
// coalesced (L2-resident, 1 MB hot from atomics).
// =====================================================================
__global__ __launch_bounds__(256)
void k3_final(const float* __restrict__ Wmat, const float* __restrict__ Smat,
              const float* __restrict__ gw, const float* __restrict__ gb,
              const float* __restrict__ ws, float* __restrict__ out) {
    __shared__ float gates[3];
    __shared__ float wrow[512];
    const int tid = threadIdx.x;
    const int vd = blockIdx.x;

    wrow[tid]       = Wmat[vd * 512 + tid];
    wrow[tid + 256] = Wmat[vd * 512 + tid + 256];

    if (tid < 64) {
        float d0 = 0.f, d1 = 0.f, d2 = 0.f;
#pragma unroll
        for (int i = 0; i < 8; ++i) {
            int kd = i * 64 + tid;
            float km = ws[WS_COLSUM + kd] * (1.0f / 65536.0f);
            d0 += gw[kd] * km;
            d1 += gw[512 + kd] * km;
            d2 += gw[1024 + kd] * km;
        }
#pragma unroll
        for (int m = 32; m; m >>= 1) {
            d0 += __shfl_xor(d0, m);
            d1 += __shfl_xor(d1, m);
            d2 += __shfl_xor(d2, m);
        }
        if (tid == 0) {
            gates[0] = 1.f / (1.f + __expf(-(d0 + gb[0])));   // alpha
            gates[1] = 1.f / (1.f + __expf(-(d1 + gb[1])));   // eta
            gates[2] = 1.f / (1.f + __expf(-(d2 + gb[2])));   // theta
        }
    }
    __syncthreads();
    const float alpha = gates[0], eta = gates[1], theta = gates[2];

    const float* G1 = ws + WS_G1;
    float g0 = 0.f, g1 = 0.f;
#pragma unroll 4
    for (int c = 0; c < 512; ++c) {
        float wc = wrow[c];
        g0 += wc * G1[c * 512 + tid];
        g1 += wc * G1[c * 512 + tid + 256];
    }
    {
        int i = vd * 512 + tid;
        float g = (g0 - ws[WS_G2 + i]) * 5.9604644775390625e-8f;   // 2/(B*VD)
        float ns = eta * Smat[i] - theta * g;
        out[OUT_S + i] = ns;
        out[OUT_W + i] = (1.f - alpha) * wrow[tid] + ns;
    }
    {
        int i = vd * 512 + tid + 256;
        float g = (g1 - ws[WS_G2 + i]) * 5.9604644775390625e-8f;
        float ns = eta * Smat[i] - theta * g;
        out[OUT_S + i] = ns;
        out[OUT_W + i] = (1.f - alpha) * wrow[tid + 256] + ns;
    }
    if (vd == 0 && tid == 0)
        out[OUT_LOSS] = ws[WS_LOSS] * 2.98023223876953125e-8f;     // 1/(B*VD)
}

extern "C" void kernel_launch(void* const* d_in, const int* in_sizes, int n_in,
                              void* d_out, int out_size, void* d_ws, size_t ws_size,
                              hipStream_t stream) {
    const float* k  = (const float*)d_in[0];
    const float* v  = (const float*)d_in[1];
    const float* W  = (const float*)d_in[2];
    const float* S  = (const float*)d_in[3];
    const float* gw = (const float*)d_in[4];
    const float* gb = (const float*)d_in[5];
    float* out = (float*)d_out;
    float* ws  = (float*)d_ws;

    // zero G2 + colsum + loss + G1 (ws is re-poisoned to 0xAA each launch)
    hipMemsetAsync(d_ws, 0, WS_END * sizeof(float), stream);

    hipLaunchKernelGGL(k12,      dim3(3072), dim3(256), 0, stream, k, v, W, out, ws);
    hipLaunchKernelGGL(k3_final, dim3(512),  dim3(256), 0, stream, W, S, gw, gb, ws, out);
}